// Round 1
// baseline (282.568 us; speedup 1.0000x reference)
//
#include <hip/hip_runtime.h>

// Problem constants (from reference)
#define B_   16
#define C_   384
#define H_   64
#define W_   64
#define G_   48
#define CPP_ 8          // C_/G_
#define PLANE (H_ * W_) // 4096
// 2*sigma^2 with sigma=0.5 -> 0.5 ; inverse = 2.0
#define INV_2SIG2 2.0f

// LDS staging: 64x64 displaced plane with 1-px zero halo -> 66 rows x 67 cols
// (67 = 66+1 pad keeps it odd -> no LDS bank conflicts on row-major reads)
#define SROWS 66
#define SCOLS 67

__global__ __launch_bounds__(256) void displace_fused_kernel(
    const float* __restrict__ inp,     // [B,C,H,W]
    const float* __restrict__ offset,  // [G,2] (x,y)
    float* __restrict__ out0,          // [B,C,H,W] displaced
    float* __restrict__ out1)          // [B,C,H,W] blurred
{
    __shared__ float s[SROWS * SCOLS];
    __shared__ float wk[9];
    __shared__ int   shv[2];

    const int p = blockIdx.x;        // plane index in [0, B*C)
    const int c = p % C_;
    const int g = c >> 3;            // CPP_ == 8

    if (threadIdx.x == 0) {
        const float ofx = offset[2 * g + 0];
        const float ofy = offset[2 * g + 1];
        const float rx = rintf(ofx);   // round-half-even == jnp.round; no ties here
        const float ry = rintf(ofy);
        const float fx = ofx - rx;
        const float fy = ofy - ry;
        float wtmp[9];
        float sum = 0.0f;
        #pragma unroll
        for (int i = 0; i < 3; ++i) {
            const float dy = (float)(i - 1) + fy;
            #pragma unroll
            for (int j = 0; j < 3; ++j) {
                const float dx = (float)(j - 1) + fx;
                const float v = __expf(-(dx * dx + dy * dy) * INV_2SIG2);
                wtmp[i * 3 + j] = v;
                sum += v;
            }
        }
        const float inv = 1.0f / sum;
        #pragma unroll
        for (int k = 0; k < 9; ++k) wk[k] = wtmp[k] * inv;
        shv[0] = (int)rx;  // ox
        shv[1] = (int)ry;  // oy
    }

    // Zero the whole staged tile (halo must be 0 = conv zero-padding)
    for (int i = threadIdx.x; i < SROWS * SCOLS; i += 256) s[i] = 0.0f;
    __syncthreads();

    const int ox = shv[0];
    const int oy = shv[1];
    const float* plane = inp + (size_t)p * PLANE;

    // Fill interior with displaced values: out[y,x] = inp[y-oy, x-ox] (0 if OOB)
    for (int idx = threadIdx.x; idx < PLANE; idx += 256) {
        const int y = idx >> 6;
        const int x = idx & 63;
        const int sy = y - oy;
        const int sx = x - ox;
        float v = 0.0f;
        if ((unsigned)sy < (unsigned)H_ && (unsigned)sx < (unsigned)W_)
            v = plane[sy * W_ + sx];
        s[(y + 1) * SCOLS + (x + 1)] = v;
    }
    __syncthreads();

    float* o0 = out0 + (size_t)p * PLANE;
    float* o1 = out1 + (size_t)p * PLANE;
    const float w0 = wk[0], w1 = wk[1], w2 = wk[2];
    const float w3 = wk[3], w4 = wk[4], w5 = wk[5];
    const float w6 = wk[6], w7 = wk[7], w8 = wk[8];

    for (int idx = threadIdx.x; idx < PLANE; idx += 256) {
        const int y = idx >> 6;
        const int x = idx & 63;
        const float* r0 = &s[y * SCOLS + x];
        const float* r1 = r0 + SCOLS;
        const float* r2 = r1 + SCOLS;
        float a;
        a  = r0[0] * w0 + r0[1] * w1 + r0[2] * w2;
        a += r1[0] * w3 + r1[1] * w4 + r1[2] * w5;
        a += r2[0] * w6 + r2[1] * w7 + r2[2] * w8;
        o0[idx] = r1[1];   // center of 3x3 window == displaced value
        o1[idx] = a;
    }
}

extern "C" void kernel_launch(void* const* d_in, const int* in_sizes, int n_in,
                              void* d_out, int out_size, void* d_ws, size_t ws_size,
                              hipStream_t stream) {
    const float* inp    = (const float*)d_in[0];
    const float* offset = (const float*)d_in[1];
    float* out0 = (float*)d_out;
    float* out1 = out0 + (size_t)B_ * C_ * PLANE;
    displace_fused_kernel<<<B_ * C_, 256, 0, stream>>>(inp, offset, out0, out1);
}

// Round 3
// 269.108 us; speedup vs baseline: 1.0500x; 1.0500x over previous
//
#include <hip/hip_runtime.h>

// Problem: B=16, C=384, H=W=64, G=48 groups (8 ch/group), K=3 gaussian, sigma=0.5
#define B_   16
#define C_   384
#define H_   64
#define W_   64
#define PLANE (H_ * W_)   // 4096
#define SCOLS 67          // 66 used cols (0..65) + 1 pad col (66) -> odd stride
#define SROWS 66

__global__ __launch_bounds__(256) void displace_fused_kernel(
    const float* __restrict__ inp,     // [B,C,H,W]
    const float* __restrict__ offset,  // [G,2] (x,y)
    float* __restrict__ out0,          // displaced
    float* __restrict__ out1)          // blurred
{
    __shared__ float s[SROWS * SCOLS];

    const int tid = threadIdx.x;
    const int p   = blockIdx.x;          // plane in [0, B*C)
    const int g   = (p % C_) >> 3;       // 8 channels per group

    // Every thread computes shift + 3x3 weights redundantly (wave-uniform).
    const float ofx = offset[2 * g + 0];
    const float ofy = offset[2 * g + 1];
    const float rx = rintf(ofx);         // half-even == jnp.round; no ties (noise ±0.45)
    const float ry = rintf(ofy);
    const float fx = ofx - rx;
    const float fy = ofy - ry;
    const int ox = (int)rx;
    const int oy = (int)ry;

    float w[9];
    {
        float sum = 0.0f;
        #pragma unroll
        for (int i = 0; i < 3; ++i) {
            const float dy = (float)(i - 1) + fy;
            #pragma unroll
            for (int j = 0; j < 3; ++j) {
                const float dx = (float)(j - 1) + fx;
                const float v = __expf(-(dx * dx + dy * dy) * 2.0f); // 1/(2*0.25)=2
                w[i * 3 + j] = v;
                sum += v;
            }
        }
        const float inv = 1.0f / sum;
        #pragma unroll
        for (int k = 0; k < 9; ++k) w[k] *= inv;
    }

    // Zero ONLY the halo: rows 0 & 65 (all cols), and cols 0 & 65 (rows 1..64).
    // NOTE: the live right halo is col 65 (windows span cols x..x+5, max 65);
    // col 66 is only the bank-conflict pad and is never read.
    // Interior (rows 1..64, cols 1..64) is fully overwritten by staging below
    // (OOB lanes write 0.0f) -> all writes disjoint, one barrier suffices.
    if (tid < 67) { s[tid] = 0.0f; s[65 * SCOLS + tid] = 0.0f; }
    if (tid < 64) { s[(tid + 1) * SCOLS] = 0.0f; s[(tid + 1) * SCOLS + 65] = 0.0f; }

    // Stage displaced plane: batch ALL 16 global loads into registers first
    // (16 outstanding loads per wave), then drain into LDS.
    const float* __restrict__ plane = inp + (size_t)p * PLANE;
    const int lane = tid & 63;
    const int wv   = tid >> 6;           // wave id 0..3; wave handles rows wv, wv+4, ...
    const int sx   = lane - ox;
    const bool vx  = (unsigned)sx < (unsigned)W_;

    float v[16];
    #pragma unroll
    for (int k = 0; k < 16; ++k) {
        const int y  = (k << 2) + wv;
        const int sy = y - oy;
        v[k] = (vx && (unsigned)sy < (unsigned)H_) ? plane[sy * W_ + sx] : 0.0f;
    }
    #pragma unroll
    for (int k = 0; k < 16; ++k) {
        const int y = (k << 2) + wv;
        s[(y + 1) * SCOLS + 1 + lane] = v[k];
    }
    __syncthreads();   // single barrier in the whole kernel

    float* __restrict__ o0 = out0 + (size_t)p * PLANE;
    float* __restrict__ o1 = out1 + (size_t)p * PLANE;

    // Each thread produces 4 consecutive pixels per iteration -> float4 stores.
    #pragma unroll
    for (int it = 0; it < 4; ++it) {
        const int base = it * 1024 + tid * 4;
        const int y = base >> 6;
        const int x = base & 63;
        const float* r0 = &s[y * SCOLS + x];      // window rows y..y+2, cols x..x+5
        const float* r1 = r0 + SCOLS;
        const float* r2 = r1 + SCOLS;

        float p0[6], p1[6], p2[6];
        #pragma unroll
        for (int j = 0; j < 6; ++j) { p0[j] = r0[j]; p1[j] = r1[j]; p2[j] = r2[j]; }

        const float4 d0 = make_float4(p1[1], p1[2], p1[3], p1[4]);

        float a0, a1, a2, a3;
        a0 = p0[0]*w[0] + p0[1]*w[1] + p0[2]*w[2]
           + p1[0]*w[3] + p1[1]*w[4] + p1[2]*w[5]
           + p2[0]*w[6] + p2[1]*w[7] + p2[2]*w[8];
        a1 = p0[1]*w[0] + p0[2]*w[1] + p0[3]*w[2]
           + p1[1]*w[3] + p1[2]*w[4] + p1[3]*w[5]
           + p2[1]*w[6] + p2[2]*w[7] + p2[3]*w[8];
        a2 = p0[2]*w[0] + p0[3]*w[1] + p0[4]*w[2]
           + p1[2]*w[3] + p1[3]*w[4] + p1[4]*w[5]
           + p2[2]*w[6] + p2[3]*w[7] + p2[4]*w[8];
        a3 = p0[3]*w[0] + p0[4]*w[1] + p0[5]*w[2]
           + p1[3]*w[3] + p1[4]*w[4] + p1[5]*w[5]
           + p2[3]*w[6] + p2[4]*w[7] + p2[5]*w[8];

        *(float4*)(o0 + base) = d0;
        *(float4*)(o1 + base) = make_float4(a0, a1, a2, a3);
    }
}

extern "C" void kernel_launch(void* const* d_in, const int* in_sizes, int n_in,
                              void* d_out, int out_size, void* d_ws, size_t ws_size,
                              hipStream_t stream) {
    const float* inp    = (const float*)d_in[0];
    const float* offset = (const float*)d_in[1];
    float* out0 = (float*)d_out;
    float* out1 = out0 + (size_t)B_ * C_ * PLANE;
    displace_fused_kernel<<<B_ * C_, 256, 0, stream>>>(inp, offset, out0, out1);
}